// Round 15
// baseline (91.864 us; speedup 1.0000x reference)
//
#include <hip/hip_runtime.h>

typedef __attribute__((ext_vector_type(4))) float f32x4;
typedef __attribute__((ext_vector_type(8))) __bf16 bf16x8;
typedef __attribute__((ext_vector_type(4))) __bf16 bf16x4;

#define QSCALE (0.125f * 1.4426950408889634f)   // d^-0.5 * log2(e), folded into q

// counted-vmcnt barriers: asm "memory" blocks mem-op motion; single post-barrier
// sched_barrier keeps LDS reads from floating above s_barrier.
#define WAITV4 do { asm volatile("s_waitcnt vmcnt(4)" ::: "memory"); \
  __builtin_amdgcn_s_barrier(); __builtin_amdgcn_sched_barrier(0); } while (0)
#define WAITV2 do { asm volatile("s_waitcnt vmcnt(2)" ::: "memory"); \
  __builtin_amdgcn_s_barrier(); __builtin_amdgcn_sched_barrier(0); } while (0)
#define WAITV0 do { asm volatile("s_waitcnt vmcnt(0)" ::: "memory"); \
  __builtin_amdgcn_s_barrier(); __builtin_amdgcn_sched_barrier(0); } while (0)

__device__ __forceinline__ void load_lds16(const void* g, void* l) {
  __builtin_amdgcn_global_load_lds(
      (const __attribute__((address_space(1))) unsigned int*)g,
      (__attribute__((address_space(3))) unsigned int*)l, 16, 0, 0);
}

__device__ __forceinline__ f32x4 mfma16(bf16x8 a, bf16x8 b, f32x4 c) {
  return __builtin_amdgcn_mfma_f32_16x16x32_bf16(a, b, c, 0, 0, 0);
}

__device__ __forceinline__ bf16x8 cat44(bf16x4 a, bf16x4 b) {
  return __builtin_shufflevector(a, b, 0, 1, 2, 3, 4, 5, 6, 7);
}

// ------------- merged prep: cast_x | transpose(w_qkv) | transpose(w_proj) -------------
// grid.x = 1536 (cast) + 1728 (wqkv 72x24) + 576 (wproj 24x24); 256 threads.

__global__ __launch_bounds__(256) void k_prep(const float* __restrict__ x,
                                              __bf16* __restrict__ xb,
                                              const float* __restrict__ wqkv,
                                              __bf16* __restrict__ wqkvT,
                                              const float* __restrict__ wproj,
                                              __bf16* __restrict__ wprojT) {
  int bid = blockIdx.x, tid = threadIdx.x;
  if (bid < 1536) {
    int i = bid * 256 + tid;                        // 8 floats per thread
    const f32x4* in4 = (const f32x4*)x;
    f32x4 a = in4[i * 2], b = in4[i * 2 + 1];
    bf16x8 o;
    o[0] = (__bf16)a[0]; o[1] = (__bf16)a[1]; o[2] = (__bf16)a[2]; o[3] = (__bf16)a[3];
    o[4] = (__bf16)b[0]; o[5] = (__bf16)b[1]; o[6] = (__bf16)b[2]; o[7] = (__bf16)b[3];
    *(bf16x8*)(xb + (size_t)i * 8) = o;
    return;
  }
  __shared__ float t[32][33];
  const float* in;
  __bf16* out;
  int C, c0, r0;
  if (bid < 3264) {
    int b2 = bid - 1536;
    in = wqkv; out = wqkvT; C = 2304;
    c0 = (b2 % 72) * 32; r0 = (b2 / 72) * 32;
  } else {
    int b2 = bid - 3264;
    in = wproj; out = wprojT; C = 768;
    c0 = (b2 % 24) * 32; r0 = (b2 / 24) * 32;
  }
  int tx = tid & 31, ty = tid >> 5;                 // 32 x 8
#pragma unroll
  for (int j = 0; j < 32; j += 8)
    t[ty + j][tx] = in[(size_t)(r0 + ty + j) * C + c0 + tx];
  __syncthreads();
#pragma unroll
  for (int j = 0; j < 32; j += 8)
    out[(size_t)(c0 + ty + j) * 768 + r0 + tx] = (__bf16)t[tx][ty + j];
}

// -------- GEMM core: TRIPLE-buffered + counted vmcnt (128x128 tile, BK=32, NT=24) --------
// smem 48K: As{0,1,2} [0,24K), Bs{0,1,2} [24K,48K). 4 gload_lds per lane per stage.

__device__ __forceinline__ void gemm_core24(const char* aB, const char* bB,
                                            char* smem, int tid, int l,
                                            int wr, int wc, f32x4 (&acc)[4][4]) {
  auto stage = [&](int buf, int kt) {
#pragma unroll
    for (int is = 0; is < 2; ++is) {
      int o = is * 4096 + tid * 16;
      int row = o >> 6, cb = (o >> 4) & 3;
      int src = row * 1536 + (((cb ^ row) & 3) << 4) + kt * 64;
      load_lds16(aB + src, smem + buf * 8192 + o);
      load_lds16(bB + src, smem + 24576 + buf * 8192 + o);
    }
  };
  auto compute = [&](int buf) {
    const __bf16* As = (const __bf16*)(smem + buf * 8192);
    const __bf16* Bs = (const __bf16*)(smem + 24576 + buf * 8192);
    bf16x8 af[4], bfr[4];
#pragma unroll
    for (int mf = 0; mf < 4; ++mf) {
      int row = wr * 64 + mf * 16 + (l & 15);
      af[mf] = *(const bf16x8*)&As[row * 32 + ((((l >> 4) ^ row) & 3) << 3)];
    }
#pragma unroll
    for (int nf = 0; nf < 4; ++nf) {
      int row = wc * 64 + nf * 16 + (l & 15);
      bfr[nf] = *(const bf16x8*)&Bs[row * 32 + ((((l >> 4) ^ row) & 3) << 3)];
    }
    __builtin_amdgcn_s_setprio(1);
#pragma unroll
    for (int mf = 0; mf < 4; ++mf)
#pragma unroll
      for (int nf = 0; nf < 4; ++nf)
        acc[mf][nf] = mfma16(af[mf], bfr[nf], acc[mf][nf]);
    __builtin_amdgcn_s_setprio(0);
  };
  stage(0, 0); stage(1, 1);
#pragma unroll 3
  for (int t = 0; t < 21; ++t) {       // 21 = 3*7, buf indices fold per unrolled copy
    WAITV4;
    stage((t + 2) % 3, t + 2);         // stages 2..22
    compute(t % 3);
  }
  WAITV4; stage(2, 23); compute(0);    // t=21
  WAITV4; compute(1);                  // t=22
  WAITV0; compute(2);                  // t=23
  __syncthreads();
}

// ---------------- QKV GEMM -> q,k,v with coalesced LDS-transposed epilogues ----------------

__global__ __launch_bounds__(256, 3) void k_qkv(const __bf16* __restrict__ A,
                                                const __bf16* __restrict__ BT,
                                                __bf16* __restrict__ qb,
                                                __bf16* __restrict__ kb,
                                                __bf16* __restrict__ vT) {
  __shared__ __align__(16) char smem[49152];
  int tid = threadIdx.x, l = tid & 63, w = tid >> 6, wr = w >> 1, wc = w & 1;
  int g = l >> 4, c = l & 15;
  int m0 = blockIdx.y * 128, n0 = blockIdx.x * 128;
  f32x4 acc[4][4] = {};
  gemm_core24((const char*)(A + (size_t)m0 * 768), (const char*)(BT + (size_t)n0 * 768),
              smem, tid, l, wr, wc, acc);
  int b = m0 >> 11, m0l = m0 & 2047;
  int sel = n0 / 768;
  int rem = n0 - sel * 768;

  if (sel == 2) {
    // build [dd 128][tok 128] bf16 tile (packed b64 writes), then coalesced vT rows
#pragma unroll
    for (int mf = 0; mf < 4; ++mf) {
      int tokb = wr * 64 + mf * 16 + 4 * g;
      int gr = tokb >> 3, low = (g & 1) << 3;
#pragma unroll
      for (int nf = 0; nf < 4; ++nf) {
        int dd = wc * 64 + nf * 16 + c;
        bf16x4 pk;
        pk[0] = (__bf16)acc[mf][nf][0]; pk[1] = (__bf16)acc[mf][nf][1];
        pk[2] = (__bf16)acc[mf][nf][2]; pk[3] = (__bf16)acc[mf][nf][3];
        *(bf16x4*)(smem + dd * 256 + (((gr ^ (dd & 15)) & 15) << 4) + low) = pk;
      }
    }
    __syncthreads();
#pragma unroll
    for (int p = 0; p < 8; ++p) {
      int idx = p * 256 + tid;
      int dd = idx >> 4, t8 = idx & 15;
      bf16x8 v = *(const bf16x8*)(smem + dd * 256 + (((t8 ^ (dd & 15)) & 15) << 4));
      int colg = rem + dd;
      int h = colg >> 6, d = colg & 63;
      *(bf16x8*)(vT + (((size_t)(b * 12 + h)) * 64 + d) * 2048 + m0l + t8 * 8) = v;
    }
  } else {
    // build [tok 128][col 128] bf16 tile, then coalesced q/k rows
    float qs = (sel == 0) ? QSCALE : 1.0f;
#pragma unroll
    for (int mf = 0; mf < 4; ++mf)
#pragma unroll
      for (int nf = 0; nf < 4; ++nf) {
        int col = wc * 64 + nf * 16 + c;
        int grc = col >> 3, lowc = (col & 7) << 1;
#pragma unroll
        for (int r = 0; r < 4; ++r) {
          int tok = wr * 64 + mf * 16 + 4 * g + r;
          *(__bf16*)(smem + tok * 256 + (((grc ^ (tok & 15)) & 15) << 4) + lowc) =
              (__bf16)(acc[mf][nf][r] * qs);
        }
      }
    __syncthreads();
    __bf16* dst0 = (sel == 0) ? qb : kb;
#pragma unroll
    for (int p = 0; p < 8; ++p) {
      int idx = p * 256 + tid;
      int tok = idx >> 4, hh = (idx >> 3) & 1, d8 = idx & 7;
      int gr = hh * 8 + d8;
      bf16x8 v = *(const bf16x8*)(smem + tok * 256 + (((gr ^ (tok & 15)) & 15) << 4));
      int h = (rem >> 6) + hh;
      *(bf16x8*)(dst0 + (((size_t)(b * 12 + h)) * 2048 + m0l + tok) * 64 + d8 * 8) = v;
    }
  }
}

// ------- flash attention: QBLK=128, KVBLK=64, split=2; K TRIPLE-buffered (staged t+2),
// V DOUBLE-buffered (staged t+1) -> 40KB LDS; counted vmcnt(2) barriers;
// kf-pipelined body; softmax denominator via MFMA-with-ones; steady loop unroll 6 -------

__global__ __launch_bounds__(256, 4) void k_attn(const __bf16* __restrict__ qb,
                                                 const __bf16* __restrict__ kb,
                                                 const __bf16* __restrict__ vT,
                                                 __bf16* __restrict__ Opart,
                                                 float* __restrict__ lpart) {
  __shared__ __align__(16) char smem[40960];   // K{0,1,2} [0,24K) V{0,1} [24K,40K)
  int tid = threadIdx.x, l = tid & 63, w = tid >> 6;
  int g = l >> 4, c = l & 15;
  // XCD-aware decode: 768 blocks = 8 XCDs x 96
  int phys = blockIdx.x;
  int lid = (phys & 7) * 96 + (phys >> 3);
  int qt = lid & 15;
  int bhsp = lid >> 4;            // 0..47
  int bh = bhsp % 24, sp = bhsp / 24;   // sp 0..1, 1024 keys each

  const char* qbase  = (const char*)qb + ((size_t)bh * 2048 + qt * 128) * 128;
  const char* kbase0 = (const char*)kb + (size_t)bh * 262144 + (size_t)sp * 131072;
  const char* vbase0 = (const char*)vT + (size_t)bh * 262144 + sp * 2048;

  // stage Q tile [128 q][64 d] into [0,16K), lift to registers
#pragma unroll
  for (int is = 0; is < 4; ++is) {
    int o = is * 4096 + tid * 16;
    int row = o >> 7, cb = (o >> 4) & 7;
    load_lds16(qbase + row * 128 + (((cb ^ row) & 7) << 4), smem + o);
  }
  __syncthreads();
  bf16x8 qf[2][2];
#pragma unroll
  for (int qi = 0; qi < 2; ++qi)
#pragma unroll
    for (int ks = 0; ks < 2; ++ks) {
      int q = w * 32 + qi * 16 + c;
      int gg = ks * 4 + g;
      qf[qi][ks] = *(const bf16x8*)(smem + q * 128 + (((gg ^ q) & 7) << 4));
    }
  __syncthreads();       // all Q reads done before K stage overwrites [0,16K)

  // lane-constant swizzled offsets (key&7 == c&7 makes XOR term kf/df-invariant)
  int low = (g & 1) << 3;
  int qkoff0 = c * 128 + (((g ^ c) & 7) << 4);            // ks=0, + kf*2048
  int qkoff1 = c * 128 + ((((4 + g) ^ c) & 7) << 4);      // ks=1, + kf*2048
  int vA0 = c * 128 + ((((g >> 1) ^ c) & 7) << 4) + low;        // ks2=0 lo, + df*2048
  int vB0 = c * 128 + ((((2 + (g >> 1)) ^ c) & 7) << 4) + low;  // ks2=0 hi
  int vA1 = c * 128 + ((((4 + (g >> 1)) ^ c) & 7) << 4) + low;  // ks2=1 lo
  int vB1 = c * 128 + ((((6 + (g >> 1)) ^ c) & 7) << 4) + low;  // ks2=1 hi

  bf16x8 ones8;
#pragma unroll
  for (int j = 0; j < 8; ++j) ones8[j] = (__bf16)1.0f;

  auto stageK = [&](int buf, int t) {          // 8KB, 2 gload_lds/lane
    const char* kbase = kbase0 + t * 8192;
#pragma unroll
    for (int is = 0; is < 2; ++is) {
      int o = is * 4096 + tid * 16;
      int r = o >> 7, cb = (o >> 4) & 7;
      load_lds16(kbase + r * 128 + (((cb ^ r) & 7) << 4), smem + buf * 8192 + o);
    }
  };
  auto stageV = [&](int buf, int t) {          // 8KB, 2 gload_lds/lane
    const char* vbase = vbase0 + t * 128;
#pragma unroll
    for (int is = 0; is < 2; ++is) {
      int o = is * 4096 + tid * 16;
      int r = o >> 7, cb = (o >> 4) & 7;
      load_lds16(vbase + (size_t)r * 4096 + (((cb ^ r) & 7) << 4),
                 smem + 24576 + buf * 8192 + o);
    }
  };

  f32x4 accL[2] = {};               // softmax denominators via MFMA-with-ones
  f32x4 accO[2][4] = {};

  auto compute = [&](int t, int kbuf, int vbuf) {
    const char* kq0 = smem + kbuf * 8192 + qkoff0;
    const char* kq1 = smem + kbuf * 8192 + qkoff1;
    const char* VsB = smem + 24576 + vbuf * 8192;
    const f32x4 z = {0.f, 0.f, 0.f, 0.f};
    f32x4 s[4][2];
    bf16x4 pkv[2][4];

    auto qk = [&](int kf) {                    // 4 MFMAs; s[kf] complete afterward
      bf16x8 k0 = *(const bf16x8*)(kq0 + kf * 2048);
      bf16x8 k1 = *(const bf16x8*)(kq1 + kf * 2048);
      __builtin_amdgcn_s_setprio(1);
      s[kf][0] = mfma16(k0, qf[0][0], z);
      s[kf][1] = mfma16(k0, qf[1][0], z);
      s[kf][0] = mfma16(k1, qf[0][1], s[kf][0]);
      s[kf][1] = mfma16(k1, qf[1][1], s[kf][1]);
      __builtin_amdgcn_s_setprio(0);
    };
    auto sm = [&](int kf) {                    // 8 exp2 + pack for one kf
      f32x4 p0, p1;
#pragma unroll
      for (int r = 0; r < 4; ++r) {
        p0[r] = __builtin_amdgcn_exp2f(s[kf][0][r]);
        p1[r] = __builtin_amdgcn_exp2f(s[kf][1][r]);
      }
      if (kf == 0 && sp == 0 && qt == 0 && t == 0 && w == 0 && g == 0 && c < 4) {
#pragma unroll
        for (int r = 0; r < 4; ++r)
          if (r != c) p0[r] = 0.f;             // post-softmax task mask (numerator only)
      }
      bf16x4 a, b;
#pragma unroll
      for (int r = 0; r < 4; ++r) { a[r] = (__bf16)p0[r]; b[r] = (__bf16)p1[r]; }
      pkv[0][kf] = a;
      pkv[1][kf] = b;
    };
    auto pv = [&](int ks2) {                   // 10 MFMAs (8 PV + 2 denominator)
      bf16x8 pa0 = cat44(pkv[0][2 * ks2], pkv[0][2 * ks2 + 1]);
      bf16x8 pa1 = cat44(pkv[1][2 * ks2], pkv[1][2 * ks2 + 1]);
      const char* p0 = VsB + (ks2 ? vA1 : vA0);
      const char* p1 = VsB + (ks2 ? vB1 : vB0);
      __builtin_amdgcn_s_setprio(1);
#pragma unroll
      for (int df = 0; df < 4; ++df) {
        bf16x4 v0 = *(const bf16x4*)(p0 + df * 2048);
        bf16x4 v1 = *(const bf16x4*)(p1 + df * 2048);
        bf16x8 vb = cat44(v0, v1);
        accO[0][df] = mfma16(pa0, vb, accO[0][df]);
        accO[1][df] = mfma16(pa1, vb, accO[1][df]);
      }
      accL[0] = mfma16(pa0, ones8, accL[0]);   // l += sum_k P (matrix pipe)
      accL[1] = mfma16(pa1, ones8, accL[1]);
      __builtin_amdgcn_s_setprio(0);
    };

    // software-pipelined emission: MFMA groups interleaved with exp/pack VALU
    qk(0); qk(1);
    sm(0);
    qk(2);
    sm(1);
    pv(0);
    qk(3);
    sm(2);
    sm(3);
    pv(1);
  };

  // prologue: order matters for vmcnt(2) (oldest-first completion): K0, V0, K1
  stageK(0, 0); stageV(0, 0); stageK(1, 1);
  // steady: queue at barrier = [K(t) V(t) K(t+1)] -> vmcnt(2) completes K(t),V(t)
#pragma unroll 6
  for (int t = 0; t < 12; ++t) {               // unroll-6 folds %3 and &1 to constants
    WAITV2;
    stageV((t + 1) & 1, t + 1);
    stageK((t + 2) % 3, t + 2);
    compute(t, t % 3, t & 1);
  }
  WAITV2; stageV(1, 13); stageK(2, 14); compute(12, 0, 0);
  WAITV2; stageV(0, 14); stageK(0, 15); compute(13, 1, 1);
  WAITV2; stageV(1, 15); compute(14, 2, 0);
  WAITV0; compute(15, 0, 1);
  __syncthreads();

  // denominator store: accL[qi][r] = l for q = w*32 + qi*16 + 4g + r (same across c)
  size_t pbase = ((size_t)sp * 24 + bh) * 2048 + qt * 128;
  if (c == 0) {
#pragma unroll
    for (int qi = 0; qi < 2; ++qi)
#pragma unroll
      for (int r = 0; r < 4; ++r)
        lpart[pbase + w * 32 + qi * 16 + 4 * g + r] = accL[qi][r];
  }

  // epilogue: per-wave [16][64] f32 transpose (4KB), 2 passes -> coalesced bf16x8 stores
  char* ep = smem + w * 4096;
#pragma unroll
  for (int mf = 0; mf < 2; ++mf) {
#pragma unroll
    for (int df = 0; df < 4; ++df) {
      int col = df * 16 + c;
      int sI = col >> 2, lowc = (col & 3) << 2;
#pragma unroll
      for (int r = 0; r < 4; ++r) {
        int rloc = 4 * g + r;
        *(float*)(ep + rloc * 256 + (((sI ^ rloc) & 15) << 4) + lowc) = accO[mf][df][r];
      }
    }
    asm volatile("s_waitcnt lgkmcnt(0)" ::: "memory");
    int rr = l >> 2, q4 = l & 3;
    f32x4 aa[4];
#pragma unroll
    for (int j = 0; j < 4; ++j) {
      int sj = q4 * 4 + j;
      aa[j] = *(const f32x4*)(ep + rr * 256 + (((sj ^ rr) & 15) << 4));
    }
    bf16x8 o0, o1;
#pragma unroll
    for (int j = 0; j < 4; ++j) { o0[j] = (__bf16)aa[0][j]; o0[4 + j] = (__bf16)aa[1][j]; }
#pragma unroll
    for (int j = 0; j < 4; ++j) { o1[j] = (__bf16)aa[2][j]; o1[4 + j] = (__bf16)aa[3][j]; }
    int q = w * 32 + mf * 16 + rr;
    char* dst = (char*)Opart + (pbase + q) * 128 + q4 * 32;
    *(bf16x8*)dst = o0;
    *(bf16x8*)(dst + 16) = o1;
  }
}

// ------- fused combine+proj, reg-staged depth-1 pipeline, compiler-managed sync ONLY ------
// Per iter: load A0/A1/lpart/B regs for tile t+1 (prefetch), compute(t) from LDS,
// combine (O0+O1)*rcp(l_h) [rl is per (token, head=kt>>1) -> must be applied per K-step],
// ds_write into buf (t+1)&1, __syncthreads. A dbuf [0,16K), B dbuf [16K,32K).

__global__ __launch_bounds__(256, 2) void k_projf(const __bf16* __restrict__ Opart,
                                                  const float* __restrict__ lpart,
                                                  const __bf16* __restrict__ BT,
                                                  const float* __restrict__ bias,
                                                  float* __restrict__ out) {
  __shared__ __align__(16) char smem[32768];
  int tid = threadIdx.x, l = tid & 63, w = tid >> 6, wr = w >> 1, wc = w & 1;
  int m0 = blockIdx.y * 128, n0 = blockIdx.x * 128;
  const char* bB = (const char*)(BT + (size_t)n0 * 768);
  int bg = m0 >> 11, m0l = m0 & 2047;
  const size_t SPL = 24ull * 2048 * 64;
  const size_t LPL = 24ull * 2048;
  int rowq = tid >> 2, cbq = tid & 3;

  bf16x8 aR0[2], aR1[2], bRg[2];
  float lsA[2], lsB[2];

  auto loadAB = [&](int kt) {                  // 10 reg loads, issue only
    int h = kt >> 1, half = kt & 1;
#pragma unroll
    for (int is = 0; is < 2; ++is) {
      int row = rowq + is * 64;
      int ch = (cbq ^ row) & 3;
      size_t lq = (size_t)(bg * 12 + h) * 2048 + m0l + row;
      size_t base = lq * 64 + half * 32 + ch * 8;
      aR0[is] = *(const bf16x8*)(Opart + base);
      aR1[is] = *(const bf16x8*)(Opart + SPL + base);
      lsA[is] = lpart[lq];
      lsB[is] = lpart[LPL + lq];
    }
#pragma unroll
    for (int is = 0; is < 2; ++is) {
      int o = is * 4096 + tid * 16;
      int r = o >> 6, c2 = (o >> 4) & 3;
      bRg[is] = *(const bf16x8*)(bB + r * 1536 + (((c2 ^ r) & 3) << 4) + kt * 64);
    }
  };
  auto writeAB = [&](int buf) {                // combine + ds_write (compiler waits on regs)
#pragma unroll
    for (int is = 0; is < 2; ++is) {
      float rl = __builtin_amdgcn_rcpf(lsA[is] + lsB[is]);
      bf16x8 o8;
#pragma unroll
      for (int j = 0; j < 8; ++j)
        o8[j] = (__bf16)(((float)aR0[is][j] + (float)aR1[is][j]) * rl);
      *(bf16x8*)(smem + buf * 8192 + is * 4096 + tid * 16) = o8;
    }
#pragma unroll
    for (int is = 0; is < 2; ++is)
      *(bf16x8*)(smem + 16384 + buf * 8192 + is * 4096 + tid * 16) = bRg[is];
  };

  f32x4 acc[4][4] = {};
  auto compute = [&](int buf) {
    const __bf16* As = (const __bf16*)(smem + buf * 8192);
    const __bf16* Bs = (const __bf16*)(smem + 16384 + buf * 8192);
    bf16x8 af[4], bfr[4];
#pragma unroll
    for (int mf = 0; mf < 4; ++mf) {
      int row = wr * 64 + mf * 16 + (l & 15);
      af[mf] = *(const bf16x8*)&As[row * 32 + ((((l >> 4) ^ row) & 3) << 3)];
    }
#pragma unroll
    for (int nf = 0; nf < 4; ++nf) {
      int row = wc * 64 + nf * 16 + (l & 15);
      bfr[nf] = *(const bf16x8*)&Bs[row * 32 + ((((l >> 4) ^ row) & 3) << 3)];
    }
    __builtin_amdgcn_s_setprio(1);
#pragma unroll
    for (int mf = 0; mf < 4; ++mf)
#pragma unroll
      for (int nf = 0; nf < 4; ++nf)
        acc[mf][nf] = mfma16(af[mf], bfr[nf], acc[mf][nf]);
    __builtin_amdgcn_s_setprio(0);
  };

  loadAB(0);
  writeAB(0);
  __syncthreads();
#pragma unroll
  for (int t = 0; t < 24; ++t) {
    if (t + 1 < 24) loadAB(t + 1);             // prefetch issued before compute
    compute(t & 1);
    if (t + 1 < 24) writeAB((t + 1) & 1);      // reg-wait lands after MFMAs
    __syncthreads();
  }

#pragma unroll
  for (int nf = 0; nf < 4; ++nf) {
    int cc = n0 + wc * 64 + nf * 16 + (l & 15);
    float bi = bias[cc];
#pragma unroll
    for (int mf = 0; mf < 4; ++mf) {
      int m = m0 + wr * 64 + mf * 16 + ((l >> 4) << 2);
#pragma unroll
      for (int r = 0; r < 4; ++r)
        out[(size_t)(m + r) * 768 + cc] = acc[mf][nf][r] + bi;
    }
  }
}

// ---------------- launch ----------------

extern "C" void kernel_launch(void* const* d_in, const int* in_sizes, int n_in,
                              void* d_out, int out_size, void* d_ws, size_t ws_size,
                              hipStream_t stream) {
  const float* x      = (const float*)d_in[0];
  const float* w_qkv  = (const float*)d_in[1];
  const float* w_proj = (const float*)d_in[2];
  const float* b_proj = (const float*)d_in[3];
  float* out = (float*)d_out;

  char* ws = (char*)d_ws;
  size_t off = 0;
  auto alloc = [&](size_t bytes) {
    char* p = ws + off;
    off += (bytes + 255) & ~(size_t)255;
    return p;
  };
  __bf16* xb     = (__bf16*)alloc(4096ull * 768 * 2);
  __bf16* wqkvT  = (__bf16*)alloc(2304ull * 768 * 2);
  __bf16* wprojT = (__bf16*)alloc(768ull * 768 * 2);
  __bf16* qb     = (__bf16*)alloc(24ull * 2048 * 64 * 2);
  __bf16* kb     = (__bf16*)alloc(24ull * 2048 * 64 * 2);
  __bf16* vT     = (__bf16*)alloc(24ull * 64 * 2048 * 2);
  __bf16* Opart  = (__bf16*)alloc(2ull * 24 * 2048 * 64 * 2);
  float*  lpart  = (float*)alloc(2ull * 24 * 2048 * 4);

  k_prep<<<3840, 256, 0, stream>>>(x, xb, w_qkv, wqkvT, w_proj, wprojT);
  k_qkv<<<dim3(18, 32), 256, 0, stream>>>(xb, wqkvT, qb, kb, vT);
  k_attn<<<768, 256, 0, stream>>>(qb, kb, vT, Opart, lpart);
  k_projf<<<dim3(6, 32), 256, 0, stream>>>(Opart, lpart, wprojT, b_proj, out);
}

// Round 16
// 85.522 us; speedup vs baseline: 1.0742x; 1.0742x over previous
//
#include <hip/hip_runtime.h>

typedef __attribute__((ext_vector_type(4))) float f32x4;
typedef __attribute__((ext_vector_type(8))) __bf16 bf16x8;
typedef __attribute__((ext_vector_type(4))) __bf16 bf16x4;

#define QSCALE (0.125f * 1.4426950408889634f)   // d^-0.5 * log2(e), folded into q

// counted-vmcnt barriers: asm "memory" blocks mem-op motion; single post-barrier
// sched_barrier keeps LDS reads from floating above s_barrier.
#define WAITV4 do { asm volatile("s_waitcnt vmcnt(4)" ::: "memory"); \
  __builtin_amdgcn_s_barrier(); __builtin_amdgcn_sched_barrier(0); } while (0)
#define WAITV2 do { asm volatile("s_waitcnt vmcnt(2)" ::: "memory"); \
  __builtin_amdgcn_s_barrier(); __builtin_amdgcn_sched_barrier(0); } while (0)
#define WAITV0 do { asm volatile("s_waitcnt vmcnt(0)" ::: "memory"); \
  __builtin_amdgcn_s_barrier(); __builtin_amdgcn_sched_barrier(0); } while (0)

__device__ __forceinline__ void load_lds16(const void* g, void* l) {
  __builtin_amdgcn_global_load_lds(
      (const __attribute__((address_space(1))) unsigned int*)g,
      (__attribute__((address_space(3))) unsigned int*)l, 16, 0, 0);
}

__device__ __forceinline__ f32x4 mfma16(bf16x8 a, bf16x8 b, f32x4 c) {
  return __builtin_amdgcn_mfma_f32_16x16x32_bf16(a, b, c, 0, 0, 0);
}

__device__ __forceinline__ bf16x8 cat44(bf16x4 a, bf16x4 b) {
  return __builtin_shufflevector(a, b, 0, 1, 2, 3, 4, 5, 6, 7);
}

// ------------- merged prep: cast_x | transpose(w_qkv) | transpose(w_proj) -------------
// grid.x = 1536 (cast) + 1728 (wqkv 72x24) + 576 (wproj 24x24); 256 threads.

__global__ __launch_bounds__(256) void k_prep(const float* __restrict__ x,
                                              __bf16* __restrict__ xb,
                                              const float* __restrict__ wqkv,
                                              __bf16* __restrict__ wqkvT,
                                              const float* __restrict__ wproj,
                                              __bf16* __restrict__ wprojT) {
  int bid = blockIdx.x, tid = threadIdx.x;
  if (bid < 1536) {
    int i = bid * 256 + tid;                        // 8 floats per thread
    const f32x4* in4 = (const f32x4*)x;
    f32x4 a = in4[i * 2], b = in4[i * 2 + 1];
    bf16x8 o;
    o[0] = (__bf16)a[0]; o[1] = (__bf16)a[1]; o[2] = (__bf16)a[2]; o[3] = (__bf16)a[3];
    o[4] = (__bf16)b[0]; o[5] = (__bf16)b[1]; o[6] = (__bf16)b[2]; o[7] = (__bf16)b[3];
    *(bf16x8*)(xb + (size_t)i * 8) = o;
    return;
  }
  __shared__ float t[32][33];
  const float* in;
  __bf16* out;
  int C, c0, r0;
  if (bid < 3264) {
    int b2 = bid - 1536;
    in = wqkv; out = wqkvT; C = 2304;
    c0 = (b2 % 72) * 32; r0 = (b2 / 72) * 32;
  } else {
    int b2 = bid - 3264;
    in = wproj; out = wprojT; C = 768;
    c0 = (b2 % 24) * 32; r0 = (b2 / 24) * 32;
  }
  int tx = tid & 31, ty = tid >> 5;                 // 32 x 8
#pragma unroll
  for (int j = 0; j < 32; j += 8)
    t[ty + j][tx] = in[(size_t)(r0 + ty + j) * C + c0 + tx];
  __syncthreads();
#pragma unroll
  for (int j = 0; j < 32; j += 8)
    out[(size_t)(c0 + ty + j) * 768 + r0 + tx] = (__bf16)t[tx][ty + j];
}

// -------- GEMM core: TRIPLE-buffered + counted vmcnt (128x128 tile, BK=32, NT=24) --------
// smem 48K: As{0,1,2} [0,24K), Bs{0,1,2} [24K,48K). 4 gload_lds per lane per stage.

__device__ __forceinline__ void gemm_core24(const char* aB, const char* bB,
                                            char* smem, int tid, int l,
                                            int wr, int wc, f32x4 (&acc)[4][4]) {
  auto stage = [&](int buf, int kt) {
#pragma unroll
    for (int is = 0; is < 2; ++is) {
      int o = is * 4096 + tid * 16;
      int row = o >> 6, cb = (o >> 4) & 3;
      int src = row * 1536 + (((cb ^ row) & 3) << 4) + kt * 64;
      load_lds16(aB + src, smem + buf * 8192 + o);
      load_lds16(bB + src, smem + 24576 + buf * 8192 + o);
    }
  };
  auto compute = [&](int buf) {
    const __bf16* As = (const __bf16*)(smem + buf * 8192);
    const __bf16* Bs = (const __bf16*)(smem + 24576 + buf * 8192);
    bf16x8 af[4], bfr[4];
#pragma unroll
    for (int mf = 0; mf < 4; ++mf) {
      int row = wr * 64 + mf * 16 + (l & 15);
      af[mf] = *(const bf16x8*)&As[row * 32 + ((((l >> 4) ^ row) & 3) << 3)];
    }
#pragma unroll
    for (int nf = 0; nf < 4; ++nf) {
      int row = wc * 64 + nf * 16 + (l & 15);
      bfr[nf] = *(const bf16x8*)&Bs[row * 32 + ((((l >> 4) ^ row) & 3) << 3)];
    }
    __builtin_amdgcn_s_setprio(1);
#pragma unroll
    for (int mf = 0; mf < 4; ++mf)
#pragma unroll
      for (int nf = 0; nf < 4; ++nf)
        acc[mf][nf] = mfma16(af[mf], bfr[nf], acc[mf][nf]);
    __builtin_amdgcn_s_setprio(0);
  };
  stage(0, 0); stage(1, 1);
#pragma unroll 3
  for (int t = 0; t < 21; ++t) {       // 21 = 3*7, buf indices fold per unrolled copy
    WAITV4;
    stage((t + 2) % 3, t + 2);         // stages 2..22
    compute(t % 3);
  }
  WAITV4; stage(2, 23); compute(0);    // t=21
  WAITV4; compute(1);                  // t=22
  WAITV0; compute(2);                  // t=23
  __syncthreads();
}

// ---------------- QKV GEMM -> q,k,v with coalesced LDS-transposed epilogues ----------------

__global__ __launch_bounds__(256, 3) void k_qkv(const __bf16* __restrict__ A,
                                                const __bf16* __restrict__ BT,
                                                __bf16* __restrict__ qb,
                                                __bf16* __restrict__ kb,
                                                __bf16* __restrict__ vT) {
  __shared__ __align__(16) char smem[49152];
  int tid = threadIdx.x, l = tid & 63, w = tid >> 6, wr = w >> 1, wc = w & 1;
  int g = l >> 4, c = l & 15;
  int m0 = blockIdx.y * 128, n0 = blockIdx.x * 128;
  f32x4 acc[4][4] = {};
  gemm_core24((const char*)(A + (size_t)m0 * 768), (const char*)(BT + (size_t)n0 * 768),
              smem, tid, l, wr, wc, acc);
  int b = m0 >> 11, m0l = m0 & 2047;
  int sel = n0 / 768;
  int rem = n0 - sel * 768;

  if (sel == 2) {
    // build [dd 128][tok 128] bf16 tile (packed b64 writes), then coalesced vT rows
#pragma unroll
    for (int mf = 0; mf < 4; ++mf) {
      int tokb = wr * 64 + mf * 16 + 4 * g;
      int gr = tokb >> 3, low = (g & 1) << 3;
#pragma unroll
      for (int nf = 0; nf < 4; ++nf) {
        int dd = wc * 64 + nf * 16 + c;
        bf16x4 pk;
        pk[0] = (__bf16)acc[mf][nf][0]; pk[1] = (__bf16)acc[mf][nf][1];
        pk[2] = (__bf16)acc[mf][nf][2]; pk[3] = (__bf16)acc[mf][nf][3];
        *(bf16x4*)(smem + dd * 256 + (((gr ^ (dd & 15)) & 15) << 4) + low) = pk;
      }
    }
    __syncthreads();
#pragma unroll
    for (int p = 0; p < 8; ++p) {
      int idx = p * 256 + tid;
      int dd = idx >> 4, t8 = idx & 15;
      bf16x8 v = *(const bf16x8*)(smem + dd * 256 + (((t8 ^ (dd & 15)) & 15) << 4));
      int colg = rem + dd;
      int h = colg >> 6, d = colg & 63;
      *(bf16x8*)(vT + (((size_t)(b * 12 + h)) * 64 + d) * 2048 + m0l + t8 * 8) = v;
    }
  } else {
    // build [tok 128][col 128] bf16 tile, then coalesced q/k rows
    float qs = (sel == 0) ? QSCALE : 1.0f;
#pragma unroll
    for (int mf = 0; mf < 4; ++mf)
#pragma unroll
      for (int nf = 0; nf < 4; ++nf) {
        int col = wc * 64 + nf * 16 + c;
        int grc = col >> 3, lowc = (col & 7) << 1;
#pragma unroll
        for (int r = 0; r < 4; ++r) {
          int tok = wr * 64 + mf * 16 + 4 * g + r;
          *(__bf16*)(smem + tok * 256 + (((grc ^ (tok & 15)) & 15) << 4) + lowc) =
              (__bf16)(acc[mf][nf][r] * qs);
        }
      }
    __syncthreads();
    __bf16* dst0 = (sel == 0) ? qb : kb;
#pragma unroll
    for (int p = 0; p < 8; ++p) {
      int idx = p * 256 + tid;
      int tok = idx >> 4, hh = (idx >> 3) & 1, d8 = idx & 7;
      int gr = hh * 8 + d8;
      bf16x8 v = *(const bf16x8*)(smem + tok * 256 + (((gr ^ (tok & 15)) & 15) << 4));
      int h = (rem >> 6) + hh;
      *(bf16x8*)(dst0 + (((size_t)(b * 12 + h)) * 2048 + m0l + tok) * 64 + d8 * 8) = v;
    }
  }
}

// ------- flash attention: QBLK=128, KVBLK=64, split=2; K TRIPLE-buffered (staged t+2),
// V DOUBLE-buffered (staged t+1) -> 40KB LDS; counted vmcnt(2) barriers;
// kf-pipelined body; softmax denominator via MFMA-with-ones; steady loop unroll 6 -------

__global__ __launch_bounds__(256, 4) void k_attn(const __bf16* __restrict__ qb,
                                                 const __bf16* __restrict__ kb,
                                                 const __bf16* __restrict__ vT,
                                                 __bf16* __restrict__ Opart,
                                                 float* __restrict__ lpart) {
  __shared__ __align__(16) char smem[40960];   // K{0,1,2} [0,24K) V{0,1} [24K,40K)
  int tid = threadIdx.x, l = tid & 63, w = tid >> 6;
  int g = l >> 4, c = l & 15;
  // XCD-aware decode: 768 blocks = 8 XCDs x 96
  int phys = blockIdx.x;
  int lid = (phys & 7) * 96 + (phys >> 3);
  int qt = lid & 15;
  int bhsp = lid >> 4;            // 0..47
  int bh = bhsp % 24, sp = bhsp / 24;   // sp 0..1, 1024 keys each

  const char* qbase  = (const char*)qb + ((size_t)bh * 2048 + qt * 128) * 128;
  const char* kbase0 = (const char*)kb + (size_t)bh * 262144 + (size_t)sp * 131072;
  const char* vbase0 = (const char*)vT + (size_t)bh * 262144 + sp * 2048;

  // stage Q tile [128 q][64 d] into [0,16K), lift to registers
#pragma unroll
  for (int is = 0; is < 4; ++is) {
    int o = is * 4096 + tid * 16;
    int row = o >> 7, cb = (o >> 4) & 7;
    load_lds16(qbase + row * 128 + (((cb ^ row) & 7) << 4), smem + o);
  }
  __syncthreads();
  bf16x8 qf[2][2];
#pragma unroll
  for (int qi = 0; qi < 2; ++qi)
#pragma unroll
    for (int ks = 0; ks < 2; ++ks) {
      int q = w * 32 + qi * 16 + c;
      int gg = ks * 4 + g;
      qf[qi][ks] = *(const bf16x8*)(smem + q * 128 + (((gg ^ q) & 7) << 4));
    }
  __syncthreads();       // all Q reads done before K stage overwrites [0,16K)

  // lane-constant swizzled offsets (key&7 == c&7 makes XOR term kf/df-invariant)
  int low = (g & 1) << 3;
  int qkoff0 = c * 128 + (((g ^ c) & 7) << 4);            // ks=0, + kf*2048
  int qkoff1 = c * 128 + ((((4 + g) ^ c) & 7) << 4);      // ks=1, + kf*2048
  int vA0 = c * 128 + ((((g >> 1) ^ c) & 7) << 4) + low;        // ks2=0 lo, + df*2048
  int vB0 = c * 128 + ((((2 + (g >> 1)) ^ c) & 7) << 4) + low;  // ks2=0 hi
  int vA1 = c * 128 + ((((4 + (g >> 1)) ^ c) & 7) << 4) + low;  // ks2=1 lo
  int vB1 = c * 128 + ((((6 + (g >> 1)) ^ c) & 7) << 4) + low;  // ks2=1 hi

  bf16x8 ones8;
#pragma unroll
  for (int j = 0; j < 8; ++j) ones8[j] = (__bf16)1.0f;

  auto stageK = [&](int buf, int t) {          // 8KB, 2 gload_lds/lane
    const char* kbase = kbase0 + t * 8192;
#pragma unroll
    for (int is = 0; is < 2; ++is) {
      int o = is * 4096 + tid * 16;
      int r = o >> 7, cb = (o >> 4) & 7;
      load_lds16(kbase + r * 128 + (((cb ^ r) & 7) << 4), smem + buf * 8192 + o);
    }
  };
  auto stageV = [&](int buf, int t) {          // 8KB, 2 gload_lds/lane
    const char* vbase = vbase0 + t * 128;
#pragma unroll
    for (int is = 0; is < 2; ++is) {
      int o = is * 4096 + tid * 16;
      int r = o >> 7, cb = (o >> 4) & 7;
      load_lds16(vbase + (size_t)r * 4096 + (((cb ^ r) & 7) << 4),
                 smem + 24576 + buf * 8192 + o);
    }
  };

  f32x4 accL[2] = {};               // softmax denominators via MFMA-with-ones
  f32x4 accO[2][4] = {};

  auto compute = [&](int t, int kbuf, int vbuf) {
    const char* kq0 = smem + kbuf * 8192 + qkoff0;
    const char* kq1 = smem + kbuf * 8192 + qkoff1;
    const char* VsB = smem + 24576 + vbuf * 8192;
    const f32x4 z = {0.f, 0.f, 0.f, 0.f};
    f32x4 s[4][2];
    bf16x4 pkv[2][4];

    auto qk = [&](int kf) {                    // 4 MFMAs; s[kf] complete afterward
      bf16x8 k0 = *(const bf16x8*)(kq0 + kf * 2048);
      bf16x8 k1 = *(const bf16x8*)(kq1 + kf * 2048);
      __builtin_amdgcn_s_setprio(1);
      s[kf][0] = mfma16(k0, qf[0][0], z);
      s[kf][1] = mfma16(k0, qf[1][0], z);
      s[kf][0] = mfma16(k1, qf[0][1], s[kf][0]);
      s[kf][1] = mfma16(k1, qf[1][1], s[kf][1]);
      __builtin_amdgcn_s_setprio(0);
    };
    auto sm = [&](int kf) {                    // 8 exp2 + pack for one kf
      f32x4 p0, p1;
#pragma unroll
      for (int r = 0; r < 4; ++r) {
        p0[r] = __builtin_amdgcn_exp2f(s[kf][0][r]);
        p1[r] = __builtin_amdgcn_exp2f(s[kf][1][r]);
      }
      if (kf == 0 && sp == 0 && qt == 0 && t == 0 && w == 0 && g == 0 && c < 4) {
#pragma unroll
        for (int r = 0; r < 4; ++r)
          if (r != c) p0[r] = 0.f;             // post-softmax task mask (numerator only)
      }
      bf16x4 a, b;
#pragma unroll
      for (int r = 0; r < 4; ++r) { a[r] = (__bf16)p0[r]; b[r] = (__bf16)p1[r]; }
      pkv[0][kf] = a;
      pkv[1][kf] = b;
    };
    auto pv = [&](int ks2) {                   // 10 MFMAs (8 PV + 2 denominator)
      bf16x8 pa0 = cat44(pkv[0][2 * ks2], pkv[0][2 * ks2 + 1]);
      bf16x8 pa1 = cat44(pkv[1][2 * ks2], pkv[1][2 * ks2 + 1]);
      const char* p0 = VsB + (ks2 ? vA1 : vA0);
      const char* p1 = VsB + (ks2 ? vB1 : vB0);
      __builtin_amdgcn_s_setprio(1);
#pragma unroll
      for (int df = 0; df < 4; ++df) {
        bf16x4 v0 = *(const bf16x4*)(p0 + df * 2048);
        bf16x4 v1 = *(const bf16x4*)(p1 + df * 2048);
        bf16x8 vb = cat44(v0, v1);
        accO[0][df] = mfma16(pa0, vb, accO[0][df]);
        accO[1][df] = mfma16(pa1, vb, accO[1][df]);
      }
      accL[0] = mfma16(pa0, ones8, accL[0]);   // l += sum_k P (matrix pipe)
      accL[1] = mfma16(pa1, ones8, accL[1]);
      __builtin_amdgcn_s_setprio(0);
    };

    // software-pipelined emission: MFMA groups interleaved with exp/pack VALU
    qk(0); qk(1);
    sm(0);
    qk(2);
    sm(1);
    pv(0);
    qk(3);
    sm(2);
    sm(3);
    pv(1);
  };

  // prologue: order matters for vmcnt(2) (oldest-first completion): K0, V0, K1
  stageK(0, 0); stageV(0, 0); stageK(1, 1);
  // steady: queue at barrier = [K(t) V(t) K(t+1)] -> vmcnt(2) completes K(t),V(t)
#pragma unroll 6
  for (int t = 0; t < 12; ++t) {               // unroll-6 folds %3 and &1 to constants
    WAITV2;
    stageV((t + 1) & 1, t + 1);
    stageK((t + 2) % 3, t + 2);
    compute(t, t % 3, t & 1);
  }
  WAITV2; stageV(1, 13); stageK(2, 14); compute(12, 0, 0);
  WAITV2; stageV(0, 14); stageK(0, 15); compute(13, 1, 1);
  WAITV2; stageV(1, 15); compute(14, 2, 0);
  WAITV0; compute(15, 0, 1);
  __syncthreads();

  // denominator store: accL[qi][r] = l for q = w*32 + qi*16 + 4g + r (same across c)
  size_t pbase = ((size_t)sp * 24 + bh) * 2048 + qt * 128;
  if (c == 0) {
#pragma unroll
    for (int qi = 0; qi < 2; ++qi)
#pragma unroll
      for (int r = 0; r < 4; ++r)
        lpart[pbase + w * 32 + qi * 16 + 4 * g + r] = accL[qi][r];
  }

  // epilogue: per-wave [16][64] f32 transpose (4KB), 2 passes -> coalesced bf16x8 stores
  char* ep = smem + w * 4096;
#pragma unroll
  for (int mf = 0; mf < 2; ++mf) {
#pragma unroll
    for (int df = 0; df < 4; ++df) {
      int col = df * 16 + c;
      int sI = col >> 2, lowc = (col & 3) << 2;
#pragma unroll
      for (int r = 0; r < 4; ++r) {
        int rloc = 4 * g + r;
        *(float*)(ep + rloc * 256 + (((sI ^ rloc) & 15) << 4) + lowc) = accO[mf][df][r];
      }
    }
    asm volatile("s_waitcnt lgkmcnt(0)" ::: "memory");
    int rr = l >> 2, q4 = l & 3;
    f32x4 aa[4];
#pragma unroll
    for (int j = 0; j < 4; ++j) {
      int sj = q4 * 4 + j;
      aa[j] = *(const f32x4*)(ep + rr * 256 + (((sj ^ rr) & 15) << 4));
    }
    bf16x8 o0, o1;
#pragma unroll
    for (int j = 0; j < 4; ++j) { o0[j] = (__bf16)aa[0][j]; o0[4 + j] = (__bf16)aa[1][j]; }
#pragma unroll
    for (int j = 0; j < 4; ++j) { o1[j] = (__bf16)aa[2][j]; o1[4 + j] = (__bf16)aa[3][j]; }
    int q = w * 32 + mf * 16 + rr;
    char* dst = (char*)Opart + (pbase + q) * 128 + q4 * 32;
    *(bf16x8*)dst = o0;
    *(bf16x8*)(dst + 16) = o1;
  }
}

// ------- combine: ao = (O0+O1)/(l0+l1); 16 bf16/thread, grid 768 -------

__global__ __launch_bounds__(256) void k_combine(const __bf16* __restrict__ Opart,
                                                 const float* __restrict__ lpart,
                                                 __bf16* __restrict__ ao) {
  int i = blockIdx.x * 256 + threadIdx.x;           // 24*2048*4 threads, 16 bf16 each
  int d4 = i & 3, q = (i >> 2) & 2047, bh = i >> 13;
  int bg = bh / 12, h = bh - bg * 12;
  const size_t SPL = 24ull * 2048 * 64;
  size_t o0 = (((size_t)bh) * 2048 + q) * 64 + d4 * 16;
  bf16x8 a0 = *(const bf16x8*)(Opart + o0);
  bf16x8 a1 = *(const bf16x8*)(Opart + o0 + 8);
  bf16x8 b0 = *(const bf16x8*)(Opart + SPL + o0);
  bf16x8 b1 = *(const bf16x8*)(Opart + SPL + o0 + 8);
  size_t lq = (size_t)bh * 2048 + q;
  float lsum = lpart[lq] + lpart[24ull * 2048 + lq];
  float rl = __builtin_amdgcn_rcpf(lsum);
  bf16x8 o0v, o1v;
#pragma unroll
  for (int j = 0; j < 8; ++j) {
    o0v[j] = (__bf16)(((float)a0[j] + (float)b0[j]) * rl);
    o1v[j] = (__bf16)(((float)a1[j] + (float)b1[j]) * rl);
  }
  __bf16* dst = ao + ((size_t)bg * 2048 + q) * 768 + h * 64 + d4 * 16;
  *(bf16x8*)dst = o0v;
  *(bf16x8*)(dst + 8) = o1v;
}

// ---------------- proj GEMM: ao[4096][768] @ wprojT + bias -> f32 out ----------------

__global__ __launch_bounds__(256, 3) void k_proj(const __bf16* __restrict__ A,
                                                 const __bf16* __restrict__ BT,
                                                 const float* __restrict__ bias,
                                                 float* __restrict__ out) {
  __shared__ __align__(16) char smem[49152];
  int tid = threadIdx.x, l = tid & 63, w = tid >> 6, wr = w >> 1, wc = w & 1;
  int m0 = blockIdx.y * 128, n0 = blockIdx.x * 128;
  f32x4 acc[4][4] = {};
  gemm_core24((const char*)(A + (size_t)m0 * 768), (const char*)(BT + (size_t)n0 * 768),
              smem, tid, l, wr, wc, acc);
#pragma unroll
  for (int nf = 0; nf < 4; ++nf) {
    int cc = n0 + wc * 64 + nf * 16 + (l & 15);
    float bi = bias[cc];
#pragma unroll
    for (int mf = 0; mf < 4; ++mf) {
      int m = m0 + wr * 64 + mf * 16 + ((l >> 4) << 2);
#pragma unroll
      for (int r = 0; r < 4; ++r)
        out[(size_t)(m + r) * 768 + cc] = acc[mf][nf][r] + bi;
    }
  }
}

// ---------------- launch ----------------

extern "C" void kernel_launch(void* const* d_in, const int* in_sizes, int n_in,
                              void* d_out, int out_size, void* d_ws, size_t ws_size,
                              hipStream_t stream) {
  const float* x      = (const float*)d_in[0];
  const float* w_qkv  = (const float*)d_in[1];
  const float* w_proj = (const float*)d_in[2];
  const float* b_proj = (const float*)d_in[3];
  float* out = (float*)d_out;

  char* ws = (char*)d_ws;
  size_t off = 0;
  auto alloc = [&](size_t bytes) {
    char* p = ws + off;
    off += (bytes + 255) & ~(size_t)255;
    return p;
  };
  __bf16* xb     = (__bf16*)alloc(4096ull * 768 * 2);
  __bf16* wqkvT  = (__bf16*)alloc(2304ull * 768 * 2);
  __bf16* wprojT = (__bf16*)alloc(768ull * 768 * 2);
  __bf16* qb     = (__bf16*)alloc(24ull * 2048 * 64 * 2);
  __bf16* kb     = (__bf16*)alloc(24ull * 2048 * 64 * 2);
  __bf16* vT     = (__bf16*)alloc(24ull * 64 * 2048 * 2);
  __bf16* ao     = (__bf16*)alloc(4096ull * 768 * 2);
  __bf16* Opart  = (__bf16*)alloc(2ull * 24 * 2048 * 64 * 2);
  float*  lpart  = (float*)alloc(2ull * 24 * 2048 * 4);

  k_prep<<<3840, 256, 0, stream>>>(x, xb, w_qkv, wqkvT, w_proj, wprojT);
  k_qkv<<<dim3(18, 32), 256, 0, stream>>>(xb, wqkvT, qb, kb, vT);
  k_attn<<<768, 256, 0, stream>>>(qb, kb, vT, Opart, lpart);
  k_combine<<<768, 256, 0, stream>>>(Opart, lpart, ao);
  k_proj<<<dim3(6, 32), 256, 0, stream>>>(ao, wprojT, b_proj, out);
}

// Round 18
// 85.120 us; speedup vs baseline: 1.0792x; 1.0047x over previous
//
#include <hip/hip_runtime.h>

typedef __attribute__((ext_vector_type(4))) float f32x4;
typedef __attribute__((ext_vector_type(8))) __bf16 bf16x8;
typedef __attribute__((ext_vector_type(4))) __bf16 bf16x4;

#define QSCALE (0.125f * 1.4426950408889634f)   // d^-0.5 * log2(e), folded into q

// counted-vmcnt barriers: asm "memory" blocks mem-op motion; single post-barrier
// sched_barrier keeps LDS reads from floating above s_barrier.
#define WAITV4 do { asm volatile("s_waitcnt vmcnt(4)" ::: "memory"); \
  __builtin_amdgcn_s_barrier(); __builtin_amdgcn_sched_barrier(0); } while (0)
#define WAITV2 do { asm volatile("s_waitcnt vmcnt(2)" ::: "memory"); \
  __builtin_amdgcn_s_barrier(); __builtin_amdgcn_sched_barrier(0); } while (0)
#define WAITV0 do { asm volatile("s_waitcnt vmcnt(0)" ::: "memory"); \
  __builtin_amdgcn_s_barrier(); __builtin_amdgcn_sched_barrier(0); } while (0)

__device__ __forceinline__ void load_lds16(const void* g, void* l) {
  __builtin_amdgcn_global_load_lds(
      (const __attribute__((address_space(1))) unsigned int*)g,
      (__attribute__((address_space(3))) unsigned int*)l, 16, 0, 0);
}

__device__ __forceinline__ f32x4 mfma16(bf16x8 a, bf16x8 b, f32x4 c) {
  return __builtin_amdgcn_mfma_f32_16x16x32_bf16(a, b, c, 0, 0, 0);
}

__device__ __forceinline__ bf16x8 cat44(bf16x4 a, bf16x4 b) {
  return __builtin_shufflevector(a, b, 0, 1, 2, 3, 4, 5, 6, 7);
}

// ------------- merged prep: cast_x | transpose(w_qkv) | transpose(w_proj) -------------
// grid.x = 1536 (cast) + 1728 (wqkv 72x24) + 576 (wproj 24x24); 256 threads.

__global__ __launch_bounds__(256) void k_prep(const float* __restrict__ x,
                                              __bf16* __restrict__ xb,
                                              const float* __restrict__ wqkv,
                                              __bf16* __restrict__ wqkvT,
                                              const float* __restrict__ wproj,
                                              __bf16* __restrict__ wprojT) {
  int bid = blockIdx.x, tid = threadIdx.x;
  if (bid < 1536) {
    int i = bid * 256 + tid;                        // 8 floats per thread
    const f32x4* in4 = (const f32x4*)x;
    f32x4 a = in4[i * 2], b = in4[i * 2 + 1];
    bf16x8 o;
    o[0] = (__bf16)a[0]; o[1] = (__bf16)a[1]; o[2] = (__bf16)a[2]; o[3] = (__bf16)a[3];
    o[4] = (__bf16)b[0]; o[5] = (__bf16)b[1]; o[6] = (__bf16)b[2]; o[7] = (__bf16)b[3];
    *(bf16x8*)(xb + (size_t)i * 8) = o;
    return;
  }
  __shared__ float t[32][33];
  const float* in;
  __bf16* out;
  int C, c0, r0;
  if (bid < 3264) {
    int b2 = bid - 1536;
    in = wqkv; out = wqkvT; C = 2304;
    c0 = (b2 % 72) * 32; r0 = (b2 / 72) * 32;
  } else {
    int b2 = bid - 3264;
    in = wproj; out = wprojT; C = 768;
    c0 = (b2 % 24) * 32; r0 = (b2 / 24) * 32;
  }
  int tx = tid & 31, ty = tid >> 5;                 // 32 x 8
#pragma unroll
  for (int j = 0; j < 32; j += 8)
    t[ty + j][tx] = in[(size_t)(r0 + ty + j) * C + c0 + tx];
  __syncthreads();
#pragma unroll
  for (int j = 0; j < 32; j += 8)
    out[(size_t)(c0 + ty + j) * 768 + r0 + tx] = (__bf16)t[tx][ty + j];
}

// -------- GEMM core: TRIPLE-buffered + counted vmcnt (128x128 tile, BK=32, NT=24) --------
// smem 48K: As{0,1,2} [0,24K), Bs{0,1,2} [24K,48K). 4 gload_lds per lane per stage.

__device__ __forceinline__ void gemm_core24(const char* aB, const char* bB,
                                            char* smem, int tid, int l,
                                            int wr, int wc, f32x4 (&acc)[4][4]) {
  auto stage = [&](int buf, int kt) {
#pragma unroll
    for (int is = 0; is < 2; ++is) {
      int o = is * 4096 + tid * 16;
      int row = o >> 6, cb = (o >> 4) & 3;
      int src = row * 1536 + (((cb ^ row) & 3) << 4) + kt * 64;
      load_lds16(aB + src, smem + buf * 8192 + o);
      load_lds16(bB + src, smem + 24576 + buf * 8192 + o);
    }
  };
  auto compute = [&](int buf) {
    const __bf16* As = (const __bf16*)(smem + buf * 8192);
    const __bf16* Bs = (const __bf16*)(smem + 24576 + buf * 8192);
    bf16x8 af[4], bfr[4];
#pragma unroll
    for (int mf = 0; mf < 4; ++mf) {
      int row = wr * 64 + mf * 16 + (l & 15);
      af[mf] = *(const bf16x8*)&As[row * 32 + ((((l >> 4) ^ row) & 3) << 3)];
    }
#pragma unroll
    for (int nf = 0; nf < 4; ++nf) {
      int row = wc * 64 + nf * 16 + (l & 15);
      bfr[nf] = *(const bf16x8*)&Bs[row * 32 + ((((l >> 4) ^ row) & 3) << 3)];
    }
    __builtin_amdgcn_s_setprio(1);
#pragma unroll
    for (int mf = 0; mf < 4; ++mf)
#pragma unroll
      for (int nf = 0; nf < 4; ++nf)
        acc[mf][nf] = mfma16(af[mf], bfr[nf], acc[mf][nf]);
    __builtin_amdgcn_s_setprio(0);
  };
  stage(0, 0); stage(1, 1);
#pragma unroll 3
  for (int t = 0; t < 21; ++t) {       // 21 = 3*7, buf indices fold per unrolled copy
    WAITV4;
    stage((t + 2) % 3, t + 2);         // stages 2..22
    compute(t % 3);
  }
  WAITV4; stage(2, 23); compute(0);    // t=21
  WAITV4; compute(1);                  // t=22
  WAITV0; compute(2);                  // t=23
  __syncthreads();
}

// ---------------- QKV GEMM -> q,k,v with coalesced LDS-transposed epilogues ----------------

__global__ __launch_bounds__(256, 3) void k_qkv(const __bf16* __restrict__ A,
                                                const __bf16* __restrict__ BT,
                                                __bf16* __restrict__ qb,
                                                __bf16* __restrict__ kb,
                                                __bf16* __restrict__ vT) {
  __shared__ __align__(16) char smem[49152];
  int tid = threadIdx.x, l = tid & 63, w = tid >> 6, wr = w >> 1, wc = w & 1;
  int g = l >> 4, c = l & 15;
  int m0 = blockIdx.y * 128, n0 = blockIdx.x * 128;
  f32x4 acc[4][4] = {};
  gemm_core24((const char*)(A + (size_t)m0 * 768), (const char*)(BT + (size_t)n0 * 768),
              smem, tid, l, wr, wc, acc);
  int b = m0 >> 11, m0l = m0 & 2047;
  int sel = n0 / 768;
  int rem = n0 - sel * 768;

  if (sel == 2) {
    // build [dd 128][tok 128] bf16 tile (packed b64 writes), then coalesced vT rows
#pragma unroll
    for (int mf = 0; mf < 4; ++mf) {
      int tokb = wr * 64 + mf * 16 + 4 * g;
      int gr = tokb >> 3, low = (g & 1) << 3;
#pragma unroll
      for (int nf = 0; nf < 4; ++nf) {
        int dd = wc * 64 + nf * 16 + c;
        bf16x4 pk;
        pk[0] = (__bf16)acc[mf][nf][0]; pk[1] = (__bf16)acc[mf][nf][1];
        pk[2] = (__bf16)acc[mf][nf][2]; pk[3] = (__bf16)acc[mf][nf][3];
        *(bf16x4*)(smem + dd * 256 + (((gr ^ (dd & 15)) & 15) << 4) + low) = pk;
      }
    }
    __syncthreads();
#pragma unroll
    for (int p = 0; p < 8; ++p) {
      int idx = p * 256 + tid;
      int dd = idx >> 4, t8 = idx & 15;
      bf16x8 v = *(const bf16x8*)(smem + dd * 256 + (((t8 ^ (dd & 15)) & 15) << 4));
      int colg = rem + dd;
      int h = colg >> 6, d = colg & 63;
      *(bf16x8*)(vT + (((size_t)(b * 12 + h)) * 64 + d) * 2048 + m0l + t8 * 8) = v;
    }
  } else {
    // build [tok 128][col 128] bf16 tile, then coalesced q/k rows
    float qs = (sel == 0) ? QSCALE : 1.0f;
#pragma unroll
    for (int mf = 0; mf < 4; ++mf)
#pragma unroll
      for (int nf = 0; nf < 4; ++nf) {
        int col = wc * 64 + nf * 16 + c;
        int grc = col >> 3, lowc = (col & 7) << 1;
#pragma unroll
        for (int r = 0; r < 4; ++r) {
          int tok = wr * 64 + mf * 16 + 4 * g + r;
          *(__bf16*)(smem + tok * 256 + (((grc ^ (tok & 15)) & 15) << 4) + lowc) =
              (__bf16)(acc[mf][nf][r] * qs);
        }
      }
    __syncthreads();
    __bf16* dst0 = (sel == 0) ? qb : kb;
#pragma unroll
    for (int p = 0; p < 8; ++p) {
      int idx = p * 256 + tid;
      int tok = idx >> 4, hh = (idx >> 3) & 1, d8 = idx & 7;
      int gr = hh * 8 + d8;
      bf16x8 v = *(const bf16x8*)(smem + tok * 256 + (((gr ^ (tok & 15)) & 15) << 4));
      int h = (rem >> 6) + hh;
      *(bf16x8*)(dst0 + (((size_t)(b * 12 + h)) * 2048 + m0l + tok) * 64 + d8 * 8) = v;
    }
  }
}

// ------- flash attention: QBLK=128, KVBLK=64, split=2; K TRIPLE-buffered (staged t+2),
// V DOUBLE-buffered (staged t+1) -> 40KB LDS; counted vmcnt(2) barriers;
// kf-pipelined body; softmax denominator via MFMA-with-ones; steady loop unroll 6 -------

__global__ __launch_bounds__(256, 4) void k_attn(const __bf16* __restrict__ qb,
                                                 const __bf16* __restrict__ kb,
                                                 const __bf16* __restrict__ vT,
                                                 __bf16* __restrict__ Opart,
                                                 float* __restrict__ lpart) {
  __shared__ __align__(16) char smem[40960];   // K{0,1,2} [0,24K) V{0,1} [24K,40K)
  int tid = threadIdx.x, l = tid & 63, w = tid >> 6;
  int g = l >> 4, c = l & 15;
  // XCD-aware decode: 768 blocks = 8 XCDs x 96
  int phys = blockIdx.x;
  int lid = (phys & 7) * 96 + (phys >> 3);
  int qt = lid & 15;
  int bhsp = lid >> 4;            // 0..47
  int bh = bhsp % 24, sp = bhsp / 24;   // sp 0..1, 1024 keys each

  const char* qbase  = (const char*)qb + ((size_t)bh * 2048 + qt * 128) * 128;
  const char* kbase0 = (const char*)kb + (size_t)bh * 262144 + (size_t)sp * 131072;
  const char* vbase0 = (const char*)vT + (size_t)bh * 262144 + sp * 2048;

  // stage Q tile [128 q][64 d] into [0,16K), lift to registers
#pragma unroll
  for (int is = 0; is < 4; ++is) {
    int o = is * 4096 + tid * 16;
    int row = o >> 7, cb = (o >> 4) & 7;
    load_lds16(qbase + row * 128 + (((cb ^ row) & 7) << 4), smem + o);
  }
  __syncthreads();
  bf16x8 qf[2][2];
#pragma unroll
  for (int qi = 0; qi < 2; ++qi)
#pragma unroll
    for (int ks = 0; ks < 2; ++ks) {
      int q = w * 32 + qi * 16 + c;
      int gg = ks * 4 + g;
      qf[qi][ks] = *(const bf16x8*)(smem + q * 128 + (((gg ^ q) & 7) << 4));
    }
  __syncthreads();       // all Q reads done before K stage overwrites [0,16K)

  // lane-constant swizzled offsets (key&7 == c&7 makes XOR term kf/df-invariant)
  int low = (g & 1) << 3;
  int qkoff0 = c * 128 + (((g ^ c) & 7) << 4);            // ks=0, + kf*2048
  int qkoff1 = c * 128 + ((((4 + g) ^ c) & 7) << 4);      // ks=1, + kf*2048
  int vA0 = c * 128 + ((((g >> 1) ^ c) & 7) << 4) + low;        // ks2=0 lo, + df*2048
  int vB0 = c * 128 + ((((2 + (g >> 1)) ^ c) & 7) << 4) + low;  // ks2=0 hi
  int vA1 = c * 128 + ((((4 + (g >> 1)) ^ c) & 7) << 4) + low;  // ks2=1 lo
  int vB1 = c * 128 + ((((6 + (g >> 1)) ^ c) & 7) << 4) + low;  // ks2=1 hi

  bf16x8 ones8;
#pragma unroll
  for (int j = 0; j < 8; ++j) ones8[j] = (__bf16)1.0f;

  auto stageK = [&](int buf, int t) {          // 8KB, 2 gload_lds/lane
    const char* kbase = kbase0 + t * 8192;
#pragma unroll
    for (int is = 0; is < 2; ++is) {
      int o = is * 4096 + tid * 16;
      int r = o >> 7, cb = (o >> 4) & 7;
      load_lds16(kbase + r * 128 + (((cb ^ r) & 7) << 4), smem + buf * 8192 + o);
    }
  };
  auto stageV = [&](int buf, int t) {          // 8KB, 2 gload_lds/lane
    const char* vbase = vbase0 + t * 128;
#pragma unroll
    for (int is = 0; is < 2; ++is) {
      int o = is * 4096 + tid * 16;
      int r = o >> 7, cb = (o >> 4) & 7;
      load_lds16(vbase + (size_t)r * 4096 + (((cb ^ r) & 7) << 4),
                 smem + 24576 + buf * 8192 + o);
    }
  };

  f32x4 accL[2] = {};               // softmax denominators via MFMA-with-ones
  f32x4 accO[2][4] = {};

  auto compute = [&](int t, int kbuf, int vbuf) {
    const char* kq0 = smem + kbuf * 8192 + qkoff0;
    const char* kq1 = smem + kbuf * 8192 + qkoff1;
    const char* VsB = smem + 24576 + vbuf * 8192;
    const f32x4 z = {0.f, 0.f, 0.f, 0.f};
    f32x4 s[4][2];
    bf16x4 pkv[2][4];

    auto qk = [&](int kf) {                    // 4 MFMAs; s[kf] complete afterward
      bf16x8 k0 = *(const bf16x8*)(kq0 + kf * 2048);
      bf16x8 k1 = *(const bf16x8*)(kq1 + kf * 2048);
      __builtin_amdgcn_s_setprio(1);
      s[kf][0] = mfma16(k0, qf[0][0], z);
      s[kf][1] = mfma16(k0, qf[1][0], z);
      s[kf][0] = mfma16(k1, qf[0][1], s[kf][0]);
      s[kf][1] = mfma16(k1, qf[1][1], s[kf][1]);
      __builtin_amdgcn_s_setprio(0);
    };
    auto sm = [&](int kf) {                    // 8 exp2 + pack for one kf
      f32x4 p0, p1;
#pragma unroll
      for (int r = 0; r < 4; ++r) {
        p0[r] = __builtin_amdgcn_exp2f(s[kf][0][r]);
        p1[r] = __builtin_amdgcn_exp2f(s[kf][1][r]);
      }
      if (kf == 0 && sp == 0 && qt == 0 && t == 0 && w == 0 && g == 0 && c < 4) {
#pragma unroll
        for (int r = 0; r < 4; ++r)
          if (r != c) p0[r] = 0.f;             // post-softmax task mask (numerator only)
      }
      bf16x4 a, b;
#pragma unroll
      for (int r = 0; r < 4; ++r) { a[r] = (__bf16)p0[r]; b[r] = (__bf16)p1[r]; }
      pkv[0][kf] = a;
      pkv[1][kf] = b;
    };
    auto pv = [&](int ks2) {                   // 10 MFMAs (8 PV + 2 denominator)
      bf16x8 pa0 = cat44(pkv[0][2 * ks2], pkv[0][2 * ks2 + 1]);
      bf16x8 pa1 = cat44(pkv[1][2 * ks2], pkv[1][2 * ks2 + 1]);
      const char* p0 = VsB + (ks2 ? vA1 : vA0);
      const char* p1 = VsB + (ks2 ? vB1 : vB0);
      __builtin_amdgcn_s_setprio(1);
#pragma unroll
      for (int df = 0; df < 4; ++df) {
        bf16x4 v0 = *(const bf16x4*)(p0 + df * 2048);
        bf16x4 v1 = *(const bf16x4*)(p1 + df * 2048);
        bf16x8 vb = cat44(v0, v1);
        accO[0][df] = mfma16(pa0, vb, accO[0][df]);
        accO[1][df] = mfma16(pa1, vb, accO[1][df]);
      }
      accL[0] = mfma16(pa0, ones8, accL[0]);   // l += sum_k P (matrix pipe)
      accL[1] = mfma16(pa1, ones8, accL[1]);
      __builtin_amdgcn_s_setprio(0);
    };

    // software-pipelined emission: MFMA groups interleaved with exp/pack VALU
    qk(0); qk(1);
    sm(0);
    qk(2);
    sm(1);
    pv(0);
    qk(3);
    sm(2);
    sm(3);
    pv(1);
  };

  // prologue: order matters for vmcnt(2) (oldest-first completion): K0, V0, K1
  stageK(0, 0); stageV(0, 0); stageK(1, 1);
  // steady: queue at barrier = [K(t) V(t) K(t+1)] -> vmcnt(2) completes K(t),V(t)
#pragma unroll 6
  for (int t = 0; t < 12; ++t) {               // unroll-6 folds %3 and &1 to constants
    WAITV2;
    stageV((t + 1) & 1, t + 1);
    stageK((t + 2) % 3, t + 2);
    compute(t, t % 3, t & 1);
  }
  WAITV2; stageV(1, 13); stageK(2, 14); compute(12, 0, 0);
  WAITV2; stageV(0, 14); stageK(0, 15); compute(13, 1, 1);
  WAITV2; stageV(1, 15); compute(14, 2, 0);
  WAITV0; compute(15, 0, 1);
  __syncthreads();

  // denominator store: accL[qi][r] = l for q = w*32 + qi*16 + 4g + r (same across c)
  size_t pbase = ((size_t)sp * 24 + bh) * 2048 + qt * 128;
  if (c == 0) {
#pragma unroll
    for (int qi = 0; qi < 2; ++qi)
#pragma unroll
      for (int r = 0; r < 4; ++r)
        lpart[pbase + w * 32 + qi * 16 + 4 * g + r] = accL[qi][r];
  }

  // epilogue: per-wave [16][64] f32 transpose (4KB), 2 passes -> coalesced bf16x8 stores
  char* ep = smem + w * 4096;
#pragma unroll
  for (int mf = 0; mf < 2; ++mf) {
#pragma unroll
    for (int df = 0; df < 4; ++df) {
      int col = df * 16 + c;
      int sI = col >> 2, lowc = (col & 3) << 2;
#pragma unroll
      for (int r = 0; r < 4; ++r) {
        int rloc = 4 * g + r;
        *(float*)(ep + rloc * 256 + (((sI ^ rloc) & 15) << 4) + lowc) = accO[mf][df][r];
      }
    }
    asm volatile("s_waitcnt lgkmcnt(0)" ::: "memory");
    int rr = l >> 2, q4 = l & 3;
    f32x4 aa[4];
#pragma unroll
    for (int j = 0; j < 4; ++j) {
      int sj = q4 * 4 + j;
      aa[j] = *(const f32x4*)(ep + rr * 256 + (((sj ^ rr) & 15) << 4));
    }
    bf16x8 o0, o1;
#pragma unroll
    for (int j = 0; j < 4; ++j) { o0[j] = (__bf16)aa[0][j]; o0[4 + j] = (__bf16)aa[1][j]; }
#pragma unroll
    for (int j = 0; j < 4; ++j) { o1[j] = (__bf16)aa[2][j]; o1[4 + j] = (__bf16)aa[3][j]; }
    int q = w * 32 + mf * 16 + rr;
    char* dst = (char*)Opart + (pbase + q) * 128 + q4 * 32;
    *(bf16x8*)dst = o0;
    *(bf16x8*)(dst + 16) = o1;
  }
}

// ---------------- combine: ao = (O0+O1)/(l0+l1), scatter to [B,N,C] bf16 ----------------

__global__ __launch_bounds__(256) void k_combine(const __bf16* __restrict__ Opart,
                                                 const float* __restrict__ lpart,
                                                 __bf16* __restrict__ ao) {
  int i = blockIdx.x * 256 + threadIdx.x;           // 24*2048*8 threads, 8 bf16 each
  int d8 = i & 7, q = (i >> 3) & 2047, bh = i >> 14;
  int bg = bh / 12, h = bh - bg * 12;
  const size_t SPL = 24ull * 2048 * 64;
  size_t o0 = (((size_t)bh) * 2048 + q) * 64 + d8 * 8;
  bf16x8 a = *(const bf16x8*)(Opart + o0);
  bf16x8 b = *(const bf16x8*)(Opart + SPL + o0);
  size_t lq = (size_t)bh * 2048 + q;
  float lsum = lpart[lq] + lpart[24ull * 2048 + lq];
  float rl = __builtin_amdgcn_rcpf(lsum);
  bf16x8 o;
#pragma unroll
  for (int j = 0; j < 8; ++j)
    o[j] = (__bf16)(((float)a[j] + (float)b[j]) * rl);
  *(bf16x8*)(ao + ((size_t)bg * 2048 + q) * 768 + h * 64 + d8 * 8) = o;
}

// ---------------- proj GEMM: ao[4096][768] @ wprojT + bias -> f32 out ----------------

__global__ __launch_bounds__(256, 3) void k_proj(const __bf16* __restrict__ A,
                                                 const __bf16* __restrict__ BT,
                                                 const float* __restrict__ bias,
                                                 float* __restrict__ out) {
  __shared__ __align__(16) char smem[49152];
  int tid = threadIdx.x, l = tid & 63, w = tid >> 6, wr = w >> 1, wc = w & 1;
  int m0 = blockIdx.y * 128, n0 = blockIdx.x * 128;
  f32x4 acc[4][4] = {};
  gemm_core24((const char*)(A + (size_t)m0 * 768), (const char*)(BT + (size_t)n0 * 768),
              smem, tid, l, wr, wc, acc);
#pragma unroll
  for (int nf = 0; nf < 4; ++nf) {
    int cc = n0 + wc * 64 + nf * 16 + (l & 15);
    float bi = bias[cc];
#pragma unroll
    for (int mf = 0; mf < 4; ++mf) {
      int m = m0 + wr * 64 + mf * 16 + ((l >> 4) << 2);
#pragma unroll
      for (int r = 0; r < 4; ++r)
        out[(size_t)(m + r) * 768 + cc] = acc[mf][nf][r] + bi;
    }
  }
}

// ---------------- launch ----------------

extern "C" void kernel_launch(void* const* d_in, const int* in_sizes, int n_in,
                              void* d_out, int out_size, void* d_ws, size_t ws_size,
                              hipStream_t stream) {
  const float* x      = (const float*)d_in[0];
  const float* w_qkv  = (const float*)d_in[1];
  const float* w_proj = (const float*)d_in[2];
  const float* b_proj = (const float*)d_in[3];
  float* out = (float*)d_out;

  char* ws = (char*)d_ws;
  size_t off = 0;
  auto alloc = [&](size_t bytes) {
    char* p = ws + off;
    off += (bytes + 255) & ~(size_t)255;
    return p;
  };
  __bf16* xb     = (__bf16*)alloc(4096ull * 768 * 2);
  __bf16* wqkvT  = (__bf16*)alloc(2304ull * 768 * 2);
  __bf16* wprojT = (__bf16*)alloc(768ull * 768 * 2);
  __bf16* qb     = (__bf16*)alloc(24ull * 2048 * 64 * 2);
  __bf16* kb     = (__bf16*)alloc(24ull * 2048 * 64 * 2);
  __bf16* vT     = (__bf16*)alloc(24ull * 64 * 2048 * 2);
  __bf16* ao     = (__bf16*)alloc(4096ull * 768 * 2);
  __bf16* Opart  = (__bf16*)alloc(2ull * 24 * 2048 * 64 * 2);
  float*  lpart  = (float*)alloc(2ull * 24 * 2048 * 4);

  k_prep<<<3840, 256, 0, stream>>>(x, xb, w_qkv, wqkvT, w_proj, wprojT);
  k_qkv<<<dim3(18, 32), 256, 0, stream>>>(xb, wqkvT, qb, kb, vT);
  k_attn<<<768, 256, 0, stream>>>(qb, kb, vT, Opart, lpart);
  k_combine<<<1536, 256, 0, stream>>>(Opart, lpart, ao);
  k_proj<<<dim3(6, 32), 256, 0, stream>>>(ao, wprojT, b_proj, out);
}